// Round 17
// baseline (89.085 us; speedup 1.0000x reference)
//
#include <hip/hip_runtime.h>
#include <hip/hip_bf16.h>
#include <stdint.h>

typedef unsigned short u16;
typedef short bs8 __attribute__((ext_vector_type(8)));    // 8 x bf16 bits
typedef unsigned short u16x4 __attribute__((ext_vector_type(4)));
typedef float vf4 __attribute__((ext_vector_type(4)));
typedef float vf16 __attribute__((ext_vector_type(16)));

__device__ __forceinline__ u16 f2bf(float f) {
    uint32_t u = __builtin_bit_cast(uint32_t, f);
    uint32_t r = u + 0x7FFFu + ((u >> 16) & 1u);   // RNE
    return (u16)(r >> 16);
}
__device__ __forceinline__ float bf2f(u16 v) {
    return __builtin_bit_cast(float, (uint32_t)v << 16);
}

#define EPSBN 1e-3f
#define L2E 1.4426950408889634f

// ---------------- P0: prep — x->bf16, weights -> packed bf16 frags ---------
// compact grid 560: [0,256) x (8/thr); [256,400) conv w (4/thr);
// [400,480) qk/v packs; [480,560) final-proj pack
__global__ __launch_bounds__(256) void prep_k(
    const float* __restrict__ x, const float* __restrict__ cw,
    const float* __restrict__ qw, const float* __restrict__ kw,
    const float* __restrict__ vw, const float* __restrict__ pjw,
    u16* __restrict__ xbf, u16* __restrict__ wpk,
    u16* __restrict__ wqk_pk, u16* __restrict__ wv_pk, u16* __restrict__ wfin_pk)
{
    if (blockIdx.x < 256) {                 // x: 524288 elems, 8/thread
        int t = blockIdx.x * 256 + threadIdx.x;
        int idx = t * 8;
        vf4 v0 = *(const vf4*)(x + idx);
        vf4 v1 = *(const vf4*)(x + idx + 4);
        u16x4 o0 = { f2bf(v0[0]), f2bf(v0[1]), f2bf(v0[2]), f2bf(v0[3]) };
        u16x4 o1 = { f2bf(v1[0]), f2bf(v1[1]), f2bf(v1[2]), f2bf(v1[3]) };
        *(u16x4*)(xbf + idx) = o0;
        *(u16x4*)(xbf + idx + 4) = o1;
    } else if (blockIdx.x < 400) {
        int t2 = (blockIdx.x - 256) * 256 + threadIdx.x;   // 0..36863
        int e4 = t2 * 4;                    // 4 consecutive cout, same cin/itap
        int cout = e4 & 63, rest = e4 >> 6;
        int cin = rest & 63, itap = rest >> 6;
        vf4 v = *(const vf4*)(cw + e4);
        u16* base = wpk + (((size_t)itap * 8 + (cin >> 3)) * 64 + cout) * 8 + (cin & 7);
#pragma unroll
        for (int k = 0; k < 4; ++k) base[k * 8] = f2bf(v[k]);
    } else if (blockIdx.x < 480) {
        int t3 = (blockIdx.x - 400) * 256 + threadIdx.x;  // 0..20479
        if (t3 < 4096) {
            int j = t3 & 7, l = (t3 >> 3) & 63, kk = (t3 >> 9) & 1, i = t3 >> 10;
            int cin = kk * 32 + ((l >> 4) << 3) + j, row = l & 15;
            float val = (row < 8) ? qw[((size_t)(i * 64 + cin)) * 8 + row] * L2E
                                  : kw[((size_t)(i * 64 + cin)) * 8 + row - 8];
            wqk_pk[t3] = f2bf(val);
        } else {
            int e = t3 - 4096;   // 0..16383
            int j = e & 7, l = (e >> 3) & 63, kk = (e >> 9) & 1;
            int ct = (e >> 10) & 3, i = e >> 12;
            int cin = kk * 32 + ((l >> 4) << 3) + j, cout = ct * 16 + (l & 15);
            wv_pk[e] = f2bf(vw[((size_t)(i * 64 + cin)) * 64 + cout]);
        }
    } else {
        int t4 = (blockIdx.x - 480) * 256 + threadIdx.x;  // 0..20479
        if (t4 < 20480) {
            int e = t4;
            int j = e & 7; e >>= 3;
            int rcol = e & 15; e >>= 4;
            int ct = e & 3; e >>= 2;
            int g = e & 3; int kc = e >> 2;
            int cin = kc * 32 + g * 8 + j, co = ct * 16 + rcol;
            wfin_pk[t4] = f2bf(pjw[(size_t)cin * 64 + co]);
        }
    }
}

// ---------------- K1: dilated 3x3 conv (MFMA) + BN + ReLU + fused q/k/v ----
// 1D grid 1024: id = pixtile*8 + ib  (ib -> XCD-local)
__global__ __launch_bounds__(256) void conv_mfma_k(
    const u16* __restrict__ xbf, const u16* __restrict__ wpk,
    const float* __restrict__ cb, const float* __restrict__ bng,
    const float* __restrict__ bnb, const float* __restrict__ bnm,
    const float* __restrict__ bnv, const u16* __restrict__ wqk_pk,
    const u16* __restrict__ wv_pk, const float* __restrict__ qb,
    const float* __restrict__ kb, const float* __restrict__ vb,
    u16* __restrict__ b_bf, u16* __restrict__ qbuf,
    u16* __restrict__ kbuf, u16* __restrict__ vT)
{
    __shared__ u16 blds[32][72];
    const int ib = blockIdx.x & 7, pixtile = blockIdx.x >> 3;
    const int i = ib >> 1, b = ib & 1, dil = 1 << i;
    const int wave = __builtin_amdgcn_readfirstlane(threadIdx.x >> 6);
    const int lane = threadIdx.x & 63;
    const int g = lane >> 4, r = lane & 15;
    const int pixsub = wave & 1, ch = wave >> 1;
    const int pixbase = pixtile * 32 + pixsub * 16;
    const int h = pixbase >> 6, w0 = pixbase & 63;

    vf4 acc0 = {0.f, 0.f, 0.f, 0.f}, acc1 = {0.f, 0.f, 0.f, 0.f};

    for (int ky = 0; ky < 3; ++ky) {
        int hy = h + (ky - 1) * dil;
        if (hy < 0 || hy >= 64) continue;
        const u16* xrow = xbf + (size_t)((b * 64 + hy) * 64) * 64;
        for (int kx = 0; kx < 3; ++kx) {
            int wx = w0 + r + (kx - 1) * dil;
            bool valid = (wx >= 0) && (wx < 64);
            const u16* ap = xrow + (valid ? wx : 0) * 64 + g * 8;
            int tap = ky * 3 + kx;
            const u16* wb = wpk + (size_t)((i * 9 + tap) * 8) * 512;
#pragma unroll
            for (int c2 = 0; c2 < 2; ++c2) {
                bs8 av = {};
                if (valid) av = *(const bs8*)(ap + c2 * 32);
                const u16* bp = wb + (size_t)(c2 * 4 + g) * 512 + (ch * 32 + r) * 8;
                bs8 bv0 = *(const bs8*)(bp);
                bs8 bv1 = *(const bs8*)(bp + 16 * 8);
                acc0 = __builtin_amdgcn_mfma_f32_16x16x32_bf16(av, bv0, acc0, 0, 0, 0);
                acc1 = __builtin_amdgcn_mfma_f32_16x16x32_bf16(av, bv1, acc1, 0, 0, 0);
            }
        }
    }
#pragma unroll
    for (int ct = 0; ct < 2; ++ct) {
        int cidx = ch * 32 + ct * 16 + r;
        int cgl = i * 64 + cidx;
        float sc = bng[cgl] * rsqrtf(bnv[cgl] + EPSBN);
        float sh = (cb[cgl] - bnm[cgl]) * sc + bnb[cgl];
        vf4 a = ct ? acc1 : acc0;
#pragma unroll
        for (int rr = 0; rr < 4; ++rr) {
            float y = fmaxf(a[rr] * sc + sh, 0.f);
            u16 yb = f2bf(y);
            b_bf[((size_t)ib * 4096 + pixbase + g * 4 + rr) * 64 + cidx] = yb;
            blds[pixsub * 16 + g * 4 + rr][cidx] = yb;
        }
    }
    __syncthreads();

    // ---- fused q,k,v projections from LDS b-tile ----
    const int ps2 = wave & 1, role = wave >> 1;
    const int n0 = pixtile * 32 + ps2 * 16;
    bs8 xb0 = *(const bs8*)(&blds[ps2 * 16 + r][g * 8]);
    bs8 xb1 = *(const bs8*)(&blds[ps2 * 16 + r][32 + g * 8]);

    if (role == 1) {
        const u16* wq = wqk_pk + (size_t)i * 1024 + lane * 8;
        bs8 wq0 = *(const bs8*)(wq);
        bs8 wq1 = *(const bs8*)(wq + 512);
        vf4 s = (vf4){0.f, 0.f, 0.f, 0.f};
        s = __builtin_amdgcn_mfma_f32_16x16x32_bf16(wq0, xb0, s, 0, 0, 0);
        s = __builtin_amdgcn_mfma_f32_16x16x32_bf16(wq1, xb1, s, 0, 0, 0);
        if (g < 2) {
            int d0 = g * 4;
            u16x4 o;
#pragma unroll
            for (int reg = 0; reg < 4; ++reg)
                o[reg] = f2bf(s[reg] + qb[i * 8 + d0 + reg] * L2E);
            *(u16x4*)(qbuf + ((size_t)ib * 4096 + n0 + r) * 8 + d0) = o;
        } else {
            int d0 = (g - 2) * 4;
            u16x4 o;
#pragma unroll
            for (int reg = 0; reg < 4; ++reg)
                o[reg] = f2bf(s[reg] + kb[i * 8 + d0 + reg]);
            *(u16x4*)(kbuf + ((size_t)ib * 4096 + n0 + r) * 8 + d0) = o;
        }
    }
#pragma unroll
    for (int c2t = 0; c2t < 2; ++c2t) {
        int ct = role * 2 + c2t;
        const u16* wv = wv_pk + ((size_t)i * 4 + ct) * 1024 + lane * 8;
        bs8 wv0 = *(const bs8*)(wv);
        bs8 wv1 = *(const bs8*)(wv + 512);
        vf4 a = (vf4){0.f, 0.f, 0.f, 0.f};
        a = __builtin_amdgcn_mfma_f32_16x16x32_bf16(wv0, xb0, a, 0, 0, 0);
        a = __builtin_amdgcn_mfma_f32_16x16x32_bf16(wv1, xb1, a, 0, 0, 0);
#pragma unroll
        for (int reg = 0; reg < 4; ++reg) {
            int row = ct * 16 + g * 4 + reg;
            vT[((size_t)ib * 64 + row) * 4096 + n0 + r] = f2bf(a[reg] + vb[i * 64 + row]);
        }
    }
}

// ---------------- K3: attention, 32x32 MFMA, 64 q/wave, 4-way key split ----
// 1D grid 512: id = (qblk*4 + ks)*8 + ib  (ib -> XCD-local)
// Epilogue stores acc regs DIRECTLY (bf16-pair u32s); combine_k inverts map.
__global__ __launch_bounds__(256) void attn_k(
    const u16* __restrict__ qbuf, const u16* __restrict__ kbuf,
    const u16* __restrict__ vT, uint32_t* __restrict__ pacc32,
    float* __restrict__ ppsum)
{
    __shared__ __align__(16) char smem[36864];
    u16* klds = (u16*)(smem + 32768);    // [256 keys][8 d]

    const int bid = blockIdx.x;
    const int ib = bid & 7, ks = (bid >> 3) & 3, qblk = bid >> 5;
    const int yb = ks * 8 + ib;
    const int wave = __builtin_amdgcn_readfirstlane(threadIdx.x >> 6);
    const int lane = threadIdx.x & 63;
    const int ql = lane & 31;
    const int hb = lane >> 5;
    const int q0 = qblk * 256 + wave * 64;
    const int tid = threadIdx.x;

    const int kb_tbl[8] = {0, 8, 4, 12, 16, 24, 20, 28};
    const int kperm = (ql & 3) + kb_tbl[ql >> 2];

    bs8 qfa = {}, qfb = {};
    if (hb == 0) {
        qfa = *(const bs8*)(qbuf + ((size_t)ib * 4096 + q0 + ql) * 8);
        qfb = *(const bs8*)(qbuf + ((size_t)ib * 4096 + q0 + 32 + ql) * 8);
    }

    vf16 a0a, a1a, a0b, a1b;
#pragma unroll
    for (int r = 0; r < 16; ++r) { a0a[r] = 0.f; a1a[r] = 0.f; a0b[r] = 0.f; a1b[r] = 0.f; }
    float psa = 0.f, psb = 0.f;

    const u16* vsrc = vT + (size_t)ib * 64 * 4096;
    const u16* ksrc = kbuf + (size_t)ib * 4096 * 8;
    const int sc_ = tid >> 2, sp_ = tid & 3;
    const char* ldsb = (const char*)smem;

    for (int kblk = ks * 4; kblk < ks * 4 + 4; ++kblk) {
        const int kb = kblk * 256;
        __syncthreads();
        {
            const u16* vrow = vsrc + (size_t)sc_ * 4096 + kb;
            char* ldsw = (char*)smem;
#pragma unroll
            for (int s = 0; s < 8; ++s) {
                int key = sp_ * 8 + s * 32;
                bs8 val = *(const bs8*)(vrow + key);
                int lin = sc_ * 512 + key * 2;
                *(bs8*)(ldsw + (lin ^ ((sc_ & 7) << 4))) = val;
            }
            bs8 kvv = *(const bs8*)(ksrc + (size_t)(kb + tid) * 8);
            *(bs8*)(klds + tid * 8) = kvv;
        }
        __syncthreads();

#pragma unroll 2
        for (int ck = 0; ck < 8; ++ck) {
            const int keyb = ck * 32;
            bs8 kA = {};
            if (hb == 0) kA = *(const bs8*)(klds + (keyb + kperm) * 8);
            vf16 z;
#pragma unroll
            for (int r = 0; r < 16; ++r) z[r] = 0.f;
            __builtin_amdgcn_s_setprio(1);
            vf16 Sa = __builtin_amdgcn_mfma_f32_32x32x16_bf16(kA, qfa, z, 0, 0, 0);
            vf16 Sb = __builtin_amdgcn_mfma_f32_32x32x16_bf16(kA, qfb, z, 0, 0, 0);
            __builtin_amdgcn_s_setprio(0);

            const int c0 = ql, c1 = 32 + ql;
            int lin00 = c0 * 512 + (keyb + hb * 8) * 2;
            int lin10 = c1 * 512 + (keyb + hb * 8) * 2;
            bs8 vA00 = *(const bs8*)(ldsb + (lin00 ^ ((c0 & 7) << 4)));
            bs8 vA01 = *(const bs8*)(ldsb + ((lin00 + 32) ^ ((c0 & 7) << 4)));
            bs8 vA10 = *(const bs8*)(ldsb + (lin10 ^ ((c1 & 7) << 4)));
            bs8 vA11 = *(const bs8*)(ldsb + ((lin10 + 32) ^ ((c1 & 7) << 4)));

            // tile a
            {
                float e[16];
#pragma unroll
                for (int r = 0; r < 16; ++r) {
                    e[r] = __builtin_amdgcn_exp2f(Sa[r]);
                    psa += e[r];
                }
                union { uint32_t u[4]; bs8 v; } p0, p1;
#pragma unroll
                for (int j = 0; j < 4; ++j) {
                    uint32_t w0, w1;
                    asm("v_cvt_pk_bf16_f32 %0, %1, %2" : "=v"(w0) : "v"(e[2 * j]), "v"(e[2 * j + 1]));
                    asm("v_cvt_pk_bf16_f32 %0, %1, %2" : "=v"(w1) : "v"(e[8 + 2 * j]), "v"(e[8 + 2 * j + 1]));
                    p0.u[j] = w0;
                    p1.u[j] = w1;
                }
                __builtin_amdgcn_s_setprio(1);
                a0a = __builtin_amdgcn_mfma_f32_32x32x16_bf16(vA00, p0.v, a0a, 0, 0, 0);
                a0a = __builtin_amdgcn_mfma_f32_32x32x16_bf16(vA01, p1.v, a0a, 0, 0, 0);
                a1a = __builtin_amdgcn_mfma_f32_32x32x16_bf16(vA10, p0.v, a1a, 0, 0, 0);
                a1a = __builtin_amdgcn_mfma_f32_32x32x16_bf16(vA11, p1.v, a1a, 0, 0, 0);
                __builtin_amdgcn_s_setprio(0);
            }
            // tile b
            {
                float e[16];
#pragma unroll
                for (int r = 0; r < 16; ++r) {
                    e[r] = __builtin_amdgcn_exp2f(Sb[r]);
                    psb += e[r];
                }
                union { uint32_t u[4]; bs8 v; } p0, p1;
#pragma unroll
                for (int j = 0; j < 4; ++j) {
                    uint32_t w0, w1;
                    asm("v_cvt_pk_bf16_f32 %0, %1, %2" : "=v"(w0) : "v"(e[2 * j]), "v"(e[2 * j + 1]));
                    asm("v_cvt_pk_bf16_f32 %0, %1, %2" : "=v"(w1) : "v"(e[8 + 2 * j]), "v"(e[8 + 2 * j + 1]));
                    p0.u[j] = w0;
                    p1.u[j] = w1;
                }
                __builtin_amdgcn_s_setprio(1);
                a0b = __builtin_amdgcn_mfma_f32_32x32x16_bf16(vA00, p0.v, a0b, 0, 0, 0);
                a0b = __builtin_amdgcn_mfma_f32_32x32x16_bf16(vA01, p1.v, a0b, 0, 0, 0);
                a1b = __builtin_amdgcn_mfma_f32_32x32x16_bf16(vA10, p0.v, a1b, 0, 0, 0);
                a1b = __builtin_amdgcn_mfma_f32_32x32x16_bf16(vA11, p1.v, a1b, 0, 0, 0);
                __builtin_amdgcn_s_setprio(0);
            }
        }
    }

    psa += __shfl_xor(psa, 32);
    psb += __shfl_xor(psb, 32);

    // epilogue: direct per-lane store of acc regs as bf16-pair u32s.
    //   word j of tile (qt,ct), lane (ql,hb) holds c-pair base
    //   c = ct*32 + 4*hb + ((j&1)<<1) + ((j>>1)<<3)   (pair: c, c+1)
#pragma unroll
    for (int t = 0; t < 2; ++t) {
        const int qt = (q0 >> 5) + t;
#pragma unroll
        for (int ct = 0; ct < 2; ++ct) {
            vf16 a = t ? (ct ? a1b : a0b) : (ct ? a1a : a0a);
            uint32_t* pdst = pacc32 + ((((size_t)yb * 128 + qt) * 2 + ct) * 512)
                           + (hb * 32 + ql) * 8;
#pragma unroll
            for (int j = 0; j < 8; ++j) {
                uint32_t w;
                asm("v_cvt_pk_bf16_f32 %0, %1, %2" : "=v"(w) : "v"(a[2 * j]), "v"(a[2 * j + 1]));
                pdst[j] = w;
            }
        }
        if (hb == 0)
            ppsum[(size_t)yb * 4096 + qt * 32 + ql] = t ? psb : psa;
    }
}

// ---------------- K3b: combine 4 partials + gamma + residual -> fusedbf ----
// 1D grid 2048: id = qb*8 + ib; block 256 = 8 q-rows x 32 c-pairs, 2 q-iters
__global__ __launch_bounds__(256) void combine_k(
    const uint32_t* __restrict__ pacc32, const float* __restrict__ ppsum,
    const u16* __restrict__ b_bf, const float* __restrict__ gamma,
    u16* __restrict__ fusedbf)
{
    const int ib = blockIdx.x & 7, qb = blockIdx.x >> 3;
    const int i = ib >> 1, b = ib & 1;
    const int c2 = (threadIdx.x & 31) * 2;
    const int ct = c2 >> 5, c5 = c2 & 31;
    const int hb = (c5 >> 2) & 1;
    const int jw = ((c5 & 2) >> 1) | ((c5 >> 3) << 1);
#pragma unroll
    for (int qi = 0; qi < 2; ++qi) {
        const int q = qb * 16 + qi * 8 + (threadIdx.x >> 5);
        const int qt = q >> 5, ql = q & 31;
        const size_t widx = (((size_t)qt * 2 + ct) * 512) + (hb * 32 + ql) * 8 + jw;
        float lo = 0.f, hi = 0.f, ps = 0.f;
#pragma unroll
        for (int s = 0; s < 4; ++s) {
            int yb = s * 8 + ib;
            uint32_t u = pacc32[(size_t)yb * (128 * 2 * 512) + widx];
            lo += bf2f((u16)(u & 0xffff));
            hi += bf2f((u16)(u >> 16));
            ps += ppsum[(size_t)yb * 4096 + q];
        }
        float rs = gamma[i] / ps;
        size_t base = ((size_t)ib * 4096 + q) * 64 + c2;
        uint32_t bv = *(const uint32_t*)(b_bf + base);
        float o0 = rs * lo + bf2f((u16)(bv & 0xffff));
        float o1 = rs * hi + bf2f((u16)(bv >> 16));
        uint32_t ou = ((uint32_t)f2bf(o1) << 16) | f2bf(o0);
        *(uint32_t*)(fusedbf + ((size_t)b * 4096 + q) * 256 + i * 64 + c2) = ou;
    }
}

// ---------------- K5: fused TF-SAME avg pool + 1x1 conv 256->16 + BN ------
// compact 1D grid 718: j0:[0,512) j1:[512,640) j2:[640,702) j3:[702,718)
__global__ __launch_bounds__(256) void pconv_k(
    const u16* __restrict__ fusedbf,
    const float* __restrict__ pw, const float* __restrict__ pbias,
    const float* __restrict__ pg, const float* __restrict__ pbe,
    const float* __restrict__ pm, const float* __restrict__ pv,
    float* __restrict__ po0, float* __restrict__ po1,
    float* __restrict__ po2, float* __restrict__ po3)
{
    __shared__ float plds[16][257];
    int id = blockIdx.x;
    int j, b, bx;
    if (id < 512)      { j = 0; b = id >> 8; bx = id & 255; }
    else if (id < 640) { int t = id - 512; j = 1; b = t >> 6; bx = t & 63; }
    else if (id < 702) { int t = id - 640; j = 2; b = (t >= 31); bx = (t >= 31) ? t - 31 : t; }
    else               { int t = id - 702; j = 3; b = t >> 3; bx = t & 7; }
    const int npix = (j == 0) ? 4096 : (j == 1) ? 1024 : (j == 2) ? 484 : 121;
    const int co = threadIdx.x & 15;
    const int pixl = threadIdx.x >> 4;
    const int pix = bx * 16 + pixl;
    const float* wp = pw + (size_t)j * 256 * 16 + co;
    float acc = pbias[j * 16 + co];

    if (j == 0) {
        const u16* ip = fusedbf + ((size_t)b * 4096 + pix) * 256;
        for (int c8 = 0; c8 < 32; ++c8) {
            bs8 xv = *(const bs8*)(ip + c8 * 8);
#pragma unroll
            for (int e = 0; e < 8; ++e)
                acc = fmaf(bf2f((u16)xv[e]), wp[(c8 * 8 + e) * 16], acc);
        }
    } else {
        const int ps = (j == 1) ? 2 : (j == 2) ? 3 : 6;
        const int od = (j == 1) ? 32 : (j == 2) ? 22 : 11;
        if (pix < npix) {
            const int oh = pix / od, ow = pix % od;
            const int pad = (od * ps - 64) >> 1;
            int hs = oh * ps - pad, wss = ow * ps - pad;
            int h0 = max(hs, 0), h1 = min(hs + ps, 64);
            int w0 = max(wss, 0), w1 = min(wss + ps, 64);
            float s[16];
#pragma unroll
            for (int e = 0; e < 16; ++e) s[e] = 0.f;
            for (int hh = h0; hh < h1; ++hh)
                for (int ww = w0; ww < w1; ++ww) {
                    const u16* p = fusedbf + (((size_t)b * 4096) + hh * 64 + ww) * 256 + co * 16;
                    bs8 v0 = *(const bs8*)(p);
                    bs8 v1 = *(const bs8*)(p + 8);
#pragma unroll
                    for (int e = 0; e < 8; ++e) {
                        s[e] += bf2f((u16)v0[e]);
                        s[8 + e] += bf2f((u16)v1[e]);
                    }
                }
            float inv = 1.f / (float)((h1 - h0) * (w1 - w0));
#pragma unroll
            for (int e = 0; e < 16; ++e) plds[pixl][co * 16 + e] = s[e] * inv;
        }
        __syncthreads();
        if (pix < npix)
            for (int c = 0; c < 256; ++c)
                acc = fmaf(plds[pixl][c], wp[c * 16], acc);
    }
    if (pix < npix) {
        acc = (acc - pm[j * 16 + co]) * (pg[j * 16 + co] * rsqrtf(pv[j * 16 + co] + EPSBN)) + pbe[j * 16 + co];
        float* outp = (j == 0) ? po0 : (j == 1) ? po1 : (j == 2) ? po2 : po3;
        outp[((size_t)b * npix + pix) * 16 + co] = acc;
    }
}

// ---------------- K6: final 320->64 GEMM (inline bilinear) + BN + ReLU -----
// grid 128, block 256 (4 waves): wave w -> pixel tile blockIdx.x*64 + w*16
__global__ __launch_bounds__(256) void final_gemm_k(
    const u16* __restrict__ fusedbf, const float* __restrict__ po0,
    const float* __restrict__ po1, const float* __restrict__ po2,
    const float* __restrict__ po3, const u16* __restrict__ wfin_pk,
    const float* __restrict__ pjb, const float* __restrict__ g,
    const float* __restrict__ be, const float* __restrict__ m,
    const float* __restrict__ v, float* __restrict__ out)
{
    const int wave = __builtin_amdgcn_readfirstlane(threadIdx.x >> 6);
    const int gpix0 = blockIdx.x * 64 + wave * 16;
    const int lane = threadIdx.x & 63;
    const int gg = lane >> 4, r = lane & 15;

    const int p = gpix0 + r;
    const int b = p >> 12, hw = p & 4095, h = hw >> 6, w = hw & 63;
    bs8 pav[2];
#pragma unroll
    for (int t = 0; t < 2; ++t) {
        int jj = t * 2 + (gg >> 1);
        int cc0 = (gg & 1) * 8;
        const float* P = (jj == 0) ? po0 : (jj == 1) ? po1 : (jj == 2) ? po2 : po3;
        int od = (jj == 0) ? 64 : (jj == 1) ? 32 : (jj == 2) ? 22 : 11;
        float scale = (float)od / 64.f;
        float fy = (h + 0.5f) * scale - 0.5f;
        int y0 = (int)floorf(fy);
        float ay = fy - (float)y0;
        int y1 = min(y0 + 1, od - 1);
        y0 = max(y0, 0);
        float fx = (w + 0.5f) * scale - 0.5f;
        int x0 = (int)floorf(fx);
        float ax = fx - (float)x0;
        int x1 = min(x0 + 1, od - 1);
        x0 = max(x0, 0);
        const float* B0 = P + (size_t)b * od * od * 16 + cc0;
        const float* p00 = B0 + (size_t)(y0 * od + x0) * 16;
        const float* p01 = B0 + (size_t)(y0 * od + x1) * 16;
        const float* p10 = B0 + (size_t)(y1 * od + x0) * 16;
        const float* p11 = B0 + (size_t)(y1 * od + x1) * 16;
        union { u16 s[8]; bs8 v8; } o;
#pragma unroll
        for (int cc = 0; cc < 8; ++cc) {
            float top = p00[cc] + ax * (p01[cc] - p00[cc]);
            float bot = p10[cc] + ax * (p11[cc] - p10[cc]);
            o.s[cc] = f2bf(top + ay * (bot - top));
        }
        pav[t] = o.v8;
    }

    vf4 acc[4];
#pragma unroll
    for (int ct = 0; ct < 4; ++ct) acc[ct] = (vf4){0.f, 0.f, 0.f, 0.f};

    const u16* fa = fusedbf + (size_t)p * 256 + gg * 8;
#pragma unroll
    for (int kc = 0; kc < 10; ++kc) {
        bs8 av = (kc < 8) ? *(const bs8*)(fa + kc * 32) : pav[kc - 8];
        const u16* wb = wfin_pk + (size_t)((kc * 4 + gg) * 4) * 128 + r * 8;
#pragma unroll
        for (int ct = 0; ct < 4; ++ct) {
            bs8 bv = *(const bs8*)(wb + ct * 128);
            acc[ct] = __builtin_amdgcn_mfma_f32_16x16x32_bf16(av, bv, acc[ct], 0, 0, 0);
        }
    }
#pragma unroll
    for (int ct = 0; ct < 4; ++ct) {
        int c = ct * 16 + r;
        float sc = g[c] * rsqrtf(v[c] + EPSBN);
        float sh = (pjb[c] - m[c]) * sc + be[c];
#pragma unroll
        for (int reg = 0; reg < 4; ++reg) {
            int pix = gpix0 + gg * 4 + reg;
            out[(size_t)pix * 64 + c] = fmaxf(acc[ct][reg] * sc + sh, 0.f);
        }
    }
}

extern "C" void kernel_launch(void* const* d_in, const int* in_sizes, int n_in,
                              void* d_out, int out_size, void* d_ws, size_t ws_size,
                              hipStream_t stream)
{
    const float* x      = (const float*)d_in[0];
    const float* conv_w = (const float*)d_in[1];
    const float* conv_b = (const float*)d_in[2];
    const float* bn_g   = (const float*)d_in[3];
    const float* bn_b   = (const float*)d_in[4];
    const float* bn_m   = (const float*)d_in[5];
    const float* bn_v   = (const float*)d_in[6];
    const float* q_w    = (const float*)d_in[7];
    const float* q_b    = (const float*)d_in[8];
    const float* k_w    = (const float*)d_in[9];
    const float* k_b    = (const float*)d_in[10];
    const float* v_w    = (const float*)d_in[11];
    const float* v_b    = (const float*)d_in[12];
    const float* gamma  = (const float*)d_in[13];
    const float* ppl_w  = (const float*)d_in[14];
    const float* ppl_b  = (const float*)d_in[15];
    const float* ppl_g  = (const float*)d_in[16];
    const float* ppl_be = (const float*)d_in[17];
    const float* ppl_m  = (const float*)d_in[18];
    const float* ppl_v  = (const float*)d_in[19];
    const float* proj_w = (const float*)d_in[20];
    const float* proj_b = (const float*)d_in[21];
    const float* pbn_g  = (const float*)d_in[22];
    const float* pbn_b  = (const float*)d_in[23];
    const float* pbn_m  = (const float*)d_in[24];
    const float* pbn_v  = (const float*)d_in[25];

    char* ws = (char*)d_ws;
    u16*  xbf     = (u16*)(ws + 0);             // 1,048,576
    u16*  wpk     = (u16*)(ws + 1048576);       //   294,912
    u16*  wqk_pk  = (u16*)(ws + 1343488);       //     8,192
    u16*  wv_pk   = (u16*)(ws + 1351680);       //    32,768
    u16*  wfin_pk = (u16*)(ws + 1384448);       //    40,960
    u16*  b_bf    = (u16*)(ws + 1425408);       // 4,194,304  [8][4096][64]
    u16*  qbuf    = (u16*)(ws + 5619712);       //   524,288
    u16*  kbuf    = (u16*)(ws + 6144000);       //   524,288
    u16*  vT      = (u16*)(ws + 6668288);       // 4,194,304  [8][64][4096]
    u16*  fusedbf = (u16*)(ws + 10862592);      // 4,194,304  [2][4096][256]
    float* ppsum  = (float*)(ws + 15056896);    //   524,288  [32][4096]
    uint32_t* pacc32 = (uint32_t*)(ws + 15581184); // 16,777,216 [32][128][2][512] u32
    // po buffers reuse the pacc region (dead after combine_k):
    float* po0    = (float*)(ws + 18917376);    //   524,288
    float* po1    = (float*)(ws + 19441664);    //   131,072
    float* po2    = (float*)(ws + 19572736);    //    61,952
    float* po3    = (float*)(ws + 19634688);    //    15,488
    float* out    = (float*)d_out;

    prep_k<<<dim3(560), 256, 0, stream>>>(
        x, conv_w, q_w, k_w, v_w, proj_w, xbf, wpk, wqk_pk, wv_pk, wfin_pk);
    conv_mfma_k<<<dim3(1024), 256, 0, stream>>>(
        xbf, wpk, conv_b, bn_g, bn_b, bn_m, bn_v,
        wqk_pk, wv_pk, q_b, k_b, v_b, b_bf, qbuf, kbuf, vT);
    attn_k<<<dim3(512), 256, 0, stream>>>(qbuf, kbuf, vT, pacc32, ppsum);
    combine_k<<<dim3(2048), 256, 0, stream>>>(pacc32, ppsum, b_bf, gamma, fusedbf);
    pconv_k<<<dim3(718), 256, 0, stream>>>(
        fusedbf, ppl_w, ppl_b, ppl_g, ppl_be, ppl_m, ppl_v,
        po0, po1, po2, po3);
    final_gemm_k<<<dim3(128), 256, 0, stream>>>(
        fusedbf, po0, po1, po2, po3, wfin_pk, proj_b, pbn_g, pbn_b, pbn_m, pbn_v, out);
}

// Round 18
// 88.670 us; speedup vs baseline: 1.0047x; 1.0047x over previous
//
#include <hip/hip_runtime.h>
#include <hip/hip_bf16.h>
#include <stdint.h>

typedef unsigned short u16;
typedef short bs8 __attribute__((ext_vector_type(8)));    // 8 x bf16 bits
typedef unsigned short u16x4 __attribute__((ext_vector_type(4)));
typedef float vf4 __attribute__((ext_vector_type(4)));
typedef float vf16 __attribute__((ext_vector_type(16)));

__device__ __forceinline__ u16 f2bf(float f) {
    uint32_t u = __builtin_bit_cast(uint32_t, f);
    uint32_t r = u + 0x7FFFu + ((u >> 16) & 1u);   // RNE
    return (u16)(r >> 16);
}
__device__ __forceinline__ float bf2f(u16 v) {
    return __builtin_bit_cast(float, (uint32_t)v << 16);
}

#define EPSBN 1e-3f
#define L2E 1.4426950408889634f

// ---------------- P0: prep — x->bf16, weights -> packed bf16 frags ---------
// compact grid 560: [0,256) x (8/thr); [256,400) conv w (4/thr);
// [400,480) qk/v packs; [480,560) final-proj pack
__global__ __launch_bounds__(256) void prep_k(
    const float* __restrict__ x, const float* __restrict__ cw,
    const float* __restrict__ qw, const float* __restrict__ kw,
    const float* __restrict__ vw, const float* __restrict__ pjw,
    u16* __restrict__ xbf, u16* __restrict__ wpk,
    u16* __restrict__ wqk_pk, u16* __restrict__ wv_pk, u16* __restrict__ wfin_pk)
{
    if (blockIdx.x < 256) {                 // x: 524288 elems, 8/thread
        int t = blockIdx.x * 256 + threadIdx.x;
        int idx = t * 8;
        vf4 v0 = *(const vf4*)(x + idx);
        vf4 v1 = *(const vf4*)(x + idx + 4);
        u16x4 o0 = { f2bf(v0[0]), f2bf(v0[1]), f2bf(v0[2]), f2bf(v0[3]) };
        u16x4 o1 = { f2bf(v1[0]), f2bf(v1[1]), f2bf(v1[2]), f2bf(v1[3]) };
        *(u16x4*)(xbf + idx) = o0;
        *(u16x4*)(xbf + idx + 4) = o1;
    } else if (blockIdx.x < 400) {
        int t2 = (blockIdx.x - 256) * 256 + threadIdx.x;   // 0..36863
        int e4 = t2 * 4;                    // 4 consecutive cout, same cin/itap
        int cout = e4 & 63, rest = e4 >> 6;
        int cin = rest & 63, itap = rest >> 6;
        vf4 v = *(const vf4*)(cw + e4);
        u16* base = wpk + (((size_t)itap * 8 + (cin >> 3)) * 64 + cout) * 8 + (cin & 7);
#pragma unroll
        for (int k = 0; k < 4; ++k) base[k * 8] = f2bf(v[k]);
    } else if (blockIdx.x < 480) {
        int t3 = (blockIdx.x - 400) * 256 + threadIdx.x;  // 0..20479
        if (t3 < 4096) {
            int j = t3 & 7, l = (t3 >> 3) & 63, kk = (t3 >> 9) & 1, i = t3 >> 10;
            int cin = kk * 32 + ((l >> 4) << 3) + j, row = l & 15;
            float val = (row < 8) ? qw[((size_t)(i * 64 + cin)) * 8 + row] * L2E
                                  : kw[((size_t)(i * 64 + cin)) * 8 + row - 8];
            wqk_pk[t3] = f2bf(val);
        } else {
            int e = t3 - 4096;   // 0..16383
            int j = e & 7, l = (e >> 3) & 63, kk = (e >> 9) & 1;
            int ct = (e >> 10) & 3, i = e >> 12;
            int cin = kk * 32 + ((l >> 4) << 3) + j, cout = ct * 16 + (l & 15);
            wv_pk[e] = f2bf(vw[((size_t)(i * 64 + cin)) * 64 + cout]);
        }
    } else {
        int t4 = (blockIdx.x - 480) * 256 + threadIdx.x;  // 0..20479
        if (t4 < 20480) {
            int e = t4;
            int j = e & 7; e >>= 3;
            int rcol = e & 15; e >>= 4;
            int ct = e & 3; e >>= 2;
            int g = e & 3; int kc = e >> 2;
            int cin = kc * 32 + g * 8 + j, co = ct * 16 + rcol;
            wfin_pk[t4] = f2bf(pjw[(size_t)cin * 64 + co]);
        }
    }
}

// ---------------- K1: dilated 3x3 conv (MFMA) + BN + ReLU + fused q/k/v ----
// 1D grid 1024: id = pixtile*8 + ib  (ib -> XCD-local)
__global__ __launch_bounds__(256) void conv_mfma_k(
    const u16* __restrict__ xbf, const u16* __restrict__ wpk,
    const float* __restrict__ cb, const float* __restrict__ bng,
    const float* __restrict__ bnb, const float* __restrict__ bnm,
    const float* __restrict__ bnv, const u16* __restrict__ wqk_pk,
    const u16* __restrict__ wv_pk, const float* __restrict__ qb,
    const float* __restrict__ kb, const float* __restrict__ vb,
    u16* __restrict__ b_bf, u16* __restrict__ qbuf,
    u16* __restrict__ kbuf, u16* __restrict__ vT)
{
    __shared__ u16 blds[32][72];
    const int ib = blockIdx.x & 7, pixtile = blockIdx.x >> 3;
    const int i = ib >> 1, b = ib & 1, dil = 1 << i;
    const int wave = __builtin_amdgcn_readfirstlane(threadIdx.x >> 6);
    const int lane = threadIdx.x & 63;
    const int g = lane >> 4, r = lane & 15;
    const int pixsub = wave & 1, ch = wave >> 1;
    const int pixbase = pixtile * 32 + pixsub * 16;
    const int h = pixbase >> 6, w0 = pixbase & 63;

    vf4 acc0 = {0.f, 0.f, 0.f, 0.f}, acc1 = {0.f, 0.f, 0.f, 0.f};

    for (int ky = 0; ky < 3; ++ky) {
        int hy = h + (ky - 1) * dil;
        if (hy < 0 || hy >= 64) continue;
        const u16* xrow = xbf + (size_t)((b * 64 + hy) * 64) * 64;
        for (int kx = 0; kx < 3; ++kx) {
            int wx = w0 + r + (kx - 1) * dil;
            bool valid = (wx >= 0) && (wx < 64);
            const u16* ap = xrow + (valid ? wx : 0) * 64 + g * 8;
            int tap = ky * 3 + kx;
            const u16* wb = wpk + (size_t)((i * 9 + tap) * 8) * 512;
#pragma unroll
            for (int c2 = 0; c2 < 2; ++c2) {
                bs8 av = {};
                if (valid) av = *(const bs8*)(ap + c2 * 32);
                const u16* bp = wb + (size_t)(c2 * 4 + g) * 512 + (ch * 32 + r) * 8;
                bs8 bv0 = *(const bs8*)(bp);
                bs8 bv1 = *(const bs8*)(bp + 16 * 8);
                acc0 = __builtin_amdgcn_mfma_f32_16x16x32_bf16(av, bv0, acc0, 0, 0, 0);
                acc1 = __builtin_amdgcn_mfma_f32_16x16x32_bf16(av, bv1, acc1, 0, 0, 0);
            }
        }
    }
#pragma unroll
    for (int ct = 0; ct < 2; ++ct) {
        int cidx = ch * 32 + ct * 16 + r;
        int cgl = i * 64 + cidx;
        float sc = bng[cgl] * rsqrtf(bnv[cgl] + EPSBN);
        float sh = (cb[cgl] - bnm[cgl]) * sc + bnb[cgl];
        vf4 a = ct ? acc1 : acc0;
#pragma unroll
        for (int rr = 0; rr < 4; ++rr) {
            float y = fmaxf(a[rr] * sc + sh, 0.f);
            u16 yb = f2bf(y);
            b_bf[((size_t)ib * 4096 + pixbase + g * 4 + rr) * 64 + cidx] = yb;
            blds[pixsub * 16 + g * 4 + rr][cidx] = yb;
        }
    }
    __syncthreads();

    // ---- fused q,k,v projections from LDS b-tile ----
    const int ps2 = wave & 1, role = wave >> 1;
    const int n0 = pixtile * 32 + ps2 * 16;
    bs8 xb0 = *(const bs8*)(&blds[ps2 * 16 + r][g * 8]);
    bs8 xb1 = *(const bs8*)(&blds[ps2 * 16 + r][32 + g * 8]);

    if (role == 1) {
        const u16* wq = wqk_pk + (size_t)i * 1024 + lane * 8;
        bs8 wq0 = *(const bs8*)(wq);
        bs8 wq1 = *(const bs8*)(wq + 512);
        vf4 s = (vf4){0.f, 0.f, 0.f, 0.f};
        s = __builtin_amdgcn_mfma_f32_16x16x32_bf16(wq0, xb0, s, 0, 0, 0);
        s = __builtin_amdgcn_mfma_f32_16x16x32_bf16(wq1, xb1, s, 0, 0, 0);
        if (g < 2) {
            int d0 = g * 4;
            u16x4 o;
#pragma unroll
            for (int reg = 0; reg < 4; ++reg)
                o[reg] = f2bf(s[reg] + qb[i * 8 + d0 + reg] * L2E);
            *(u16x4*)(qbuf + ((size_t)ib * 4096 + n0 + r) * 8 + d0) = o;
        } else {
            int d0 = (g - 2) * 4;
            u16x4 o;
#pragma unroll
            for (int reg = 0; reg < 4; ++reg)
                o[reg] = f2bf(s[reg] + kb[i * 8 + d0 + reg]);
            *(u16x4*)(kbuf + ((size_t)ib * 4096 + n0 + r) * 8 + d0) = o;
        }
    }
#pragma unroll
    for (int c2t = 0; c2t < 2; ++c2t) {
        int ct = role * 2 + c2t;
        const u16* wv = wv_pk + ((size_t)i * 4 + ct) * 1024 + lane * 8;
        bs8 wv0 = *(const bs8*)(wv);
        bs8 wv1 = *(const bs8*)(wv + 512);
        vf4 a = (vf4){0.f, 0.f, 0.f, 0.f};
        a = __builtin_amdgcn_mfma_f32_16x16x32_bf16(wv0, xb0, a, 0, 0, 0);
        a = __builtin_amdgcn_mfma_f32_16x16x32_bf16(wv1, xb1, a, 0, 0, 0);
#pragma unroll
        for (int reg = 0; reg < 4; ++reg) {
            int row = ct * 16 + g * 4 + reg;
            vT[((size_t)ib * 64 + row) * 4096 + n0 + r] = f2bf(a[reg] + vb[i * 64 + row]);
        }
    }
}

// ---------------- K3: attention, 32x32 MFMA, 64 q/wave, 4-way key split ----
// 1D grid 512: id = (qblk*4 + ks)*8 + ib  (ib -> XCD-local)
// Epilogue stores acc regs DIRECTLY (bf16-pair u32s); combine_k inverts map.
__global__ __launch_bounds__(256) void attn_k(
    const u16* __restrict__ qbuf, const u16* __restrict__ kbuf,
    const u16* __restrict__ vT, uint32_t* __restrict__ pacc32,
    float* __restrict__ ppsum)
{
    __shared__ __align__(16) char smem[36864];
    u16* klds = (u16*)(smem + 32768);    // [256 keys][8 d]

    const int bid = blockIdx.x;
    const int ib = bid & 7, ks = (bid >> 3) & 3, qblk = bid >> 5;
    const int yb = ks * 8 + ib;
    const int wave = __builtin_amdgcn_readfirstlane(threadIdx.x >> 6);
    const int lane = threadIdx.x & 63;
    const int ql = lane & 31;
    const int hb = lane >> 5;
    const int q0 = qblk * 256 + wave * 64;
    const int tid = threadIdx.x;

    const int kb_tbl[8] = {0, 8, 4, 12, 16, 24, 20, 28};
    const int kperm = (ql & 3) + kb_tbl[ql >> 2];

    bs8 qfa = {}, qfb = {};
    if (hb == 0) {
        qfa = *(const bs8*)(qbuf + ((size_t)ib * 4096 + q0 + ql) * 8);
        qfb = *(const bs8*)(qbuf + ((size_t)ib * 4096 + q0 + 32 + ql) * 8);
    }

    vf16 a0a, a1a, a0b, a1b;
#pragma unroll
    for (int r = 0; r < 16; ++r) { a0a[r] = 0.f; a1a[r] = 0.f; a0b[r] = 0.f; a1b[r] = 0.f; }
    float psa = 0.f, psb = 0.f;

    const u16* vsrc = vT + (size_t)ib * 64 * 4096;
    const u16* ksrc = kbuf + (size_t)ib * 4096 * 8;
    const int sc_ = tid >> 2, sp_ = tid & 3;
    const char* ldsb = (const char*)smem;

    for (int kblk = ks * 4; kblk < ks * 4 + 4; ++kblk) {
        const int kb = kblk * 256;
        __syncthreads();
        {
            const u16* vrow = vsrc + (size_t)sc_ * 4096 + kb;
            char* ldsw = (char*)smem;
#pragma unroll
            for (int s = 0; s < 8; ++s) {
                int key = sp_ * 8 + s * 32;
                bs8 val = *(const bs8*)(vrow + key);
                int lin = sc_ * 512 + key * 2;
                *(bs8*)(ldsw + (lin ^ ((sc_ & 7) << 4))) = val;
            }
            bs8 kvv = *(const bs8*)(ksrc + (size_t)(kb + tid) * 8);
            *(bs8*)(klds + tid * 8) = kvv;
        }
        __syncthreads();

#pragma unroll 2
        for (int ck = 0; ck < 8; ++ck) {
            const int keyb = ck * 32;
            bs8 kA = {};
            if (hb == 0) kA = *(const bs8*)(klds + (keyb + kperm) * 8);
            vf16 z;
#pragma unroll
            for (int r = 0; r < 16; ++r) z[r] = 0.f;
            __builtin_amdgcn_s_setprio(1);
            vf16 Sa = __builtin_amdgcn_mfma_f32_32x32x16_bf16(kA, qfa, z, 0, 0, 0);
            vf16 Sb = __builtin_amdgcn_mfma_f32_32x32x16_bf16(kA, qfb, z, 0, 0, 0);
            __builtin_amdgcn_s_setprio(0);

            const int c0 = ql, c1 = 32 + ql;
            int lin00 = c0 * 512 + (keyb + hb * 8) * 2;
            int lin10 = c1 * 512 + (keyb + hb * 8) * 2;
            bs8 vA00 = *(const bs8*)(ldsb + (lin00 ^ ((c0 & 7) << 4)));
            bs8 vA01 = *(const bs8*)(ldsb + ((lin00 + 32) ^ ((c0 & 7) << 4)));
            bs8 vA10 = *(const bs8*)(ldsb + (lin10 ^ ((c1 & 7) << 4)));
            bs8 vA11 = *(const bs8*)(ldsb + ((lin10 + 32) ^ ((c1 & 7) << 4)));

            // tile a
            {
                float e[16];
#pragma unroll
                for (int r = 0; r < 16; ++r) {
                    e[r] = __builtin_amdgcn_exp2f(Sa[r]);
                    psa += e[r];
                }
                union { uint32_t u[4]; bs8 v; } p0, p1;
#pragma unroll
                for (int j = 0; j < 4; ++j) {
                    uint32_t w0, w1;
                    asm("v_cvt_pk_bf16_f32 %0, %1, %2" : "=v"(w0) : "v"(e[2 * j]), "v"(e[2 * j + 1]));
                    asm("v_cvt_pk_bf16_f32 %0, %1, %2" : "=v"(w1) : "v"(e[8 + 2 * j]), "v"(e[8 + 2 * j + 1]));
                    p0.u[j] = w0;
                    p1.u[j] = w1;
                }
                __builtin_amdgcn_s_setprio(1);
                a0a = __builtin_amdgcn_mfma_f32_32x32x16_bf16(vA00, p0.v, a0a, 0, 0, 0);
                a0a = __builtin_amdgcn_mfma_f32_32x32x16_bf16(vA01, p1.v, a0a, 0, 0, 0);
                a1a = __builtin_amdgcn_mfma_f32_32x32x16_bf16(vA10, p0.v, a1a, 0, 0, 0);
                a1a = __builtin_amdgcn_mfma_f32_32x32x16_bf16(vA11, p1.v, a1a, 0, 0, 0);
                __builtin_amdgcn_s_setprio(0);
            }
            // tile b
            {
                float e[16];
#pragma unroll
                for (int r = 0; r < 16; ++r) {
                    e[r] = __builtin_amdgcn_exp2f(Sb[r]);
                    psb += e[r];
                }
                union { uint32_t u[4]; bs8 v; } p0, p1;
#pragma unroll
                for (int j = 0; j < 4; ++j) {
                    uint32_t w0, w1;
                    asm("v_cvt_pk_bf16_f32 %0, %1, %2" : "=v"(w0) : "v"(e[2 * j]), "v"(e[2 * j + 1]));
                    asm("v_cvt_pk_bf16_f32 %0, %1, %2" : "=v"(w1) : "v"(e[8 + 2 * j]), "v"(e[8 + 2 * j + 1]));
                    p0.u[j] = w0;
                    p1.u[j] = w1;
                }
                __builtin_amdgcn_s_setprio(1);
                a0b = __builtin_amdgcn_mfma_f32_32x32x16_bf16(vA00, p0.v, a0b, 0, 0, 0);
                a0b = __builtin_amdgcn_mfma_f32_32x32x16_bf16(vA01, p1.v, a0b, 0, 0, 0);
                a1b = __builtin_amdgcn_mfma_f32_32x32x16_bf16(vA10, p0.v, a1b, 0, 0, 0);
                a1b = __builtin_amdgcn_mfma_f32_32x32x16_bf16(vA11, p1.v, a1b, 0, 0, 0);
                __builtin_amdgcn_s_setprio(0);
            }
        }
    }

    psa += __shfl_xor(psa, 32);
    psb += __shfl_xor(psb, 32);

    // epilogue: direct per-lane store of acc regs as bf16-pair u32s.
    //   word j of tile (qt,ct), lane (ql,hb) holds c-pair base
    //   c = ct*32 + 4*hb + ((j&1)<<1) + ((j>>1)<<3)   (pair: c, c+1)
#pragma unroll
    for (int t = 0; t < 2; ++t) {
        const int qt = (q0 >> 5) + t;
#pragma unroll
        for (int ct = 0; ct < 2; ++ct) {
            vf16 a = t ? (ct ? a1b : a0b) : (ct ? a1a : a0a);
            uint32_t* pdst = pacc32 + ((((size_t)yb * 128 + qt) * 2 + ct) * 512)
                           + (hb * 32 + ql) * 8;
#pragma unroll
            for (int j = 0; j < 8; ++j) {
                uint32_t w;
                asm("v_cvt_pk_bf16_f32 %0, %1, %2" : "=v"(w) : "v"(a[2 * j]), "v"(a[2 * j + 1]));
                pdst[j] = w;
            }
        }
        if (hb == 0)
            ppsum[(size_t)yb * 4096 + qt * 32 + ql] = t ? psb : psa;
    }
}

// ---------------- K3b: combine 4 partials + gamma + residual -> fusedbf ----
// 1D grid 4096: id = qb*8 + ib; block 256 = 8 q-rows x 32 channel-pairs
__global__ __launch_bounds__(256) void combine_k(
    const uint32_t* __restrict__ pacc32, const float* __restrict__ ppsum,
    const u16* __restrict__ b_bf, const float* __restrict__ gamma,
    u16* __restrict__ fusedbf)
{
    const int ib = blockIdx.x & 7, qb = blockIdx.x >> 3;
    const int i = ib >> 1, b = ib & 1;
    const int q = qb * 8 + (threadIdx.x >> 5);
    const int c2 = (threadIdx.x & 31) * 2;
    // inverse reg-map: c2 even; c5 = c2&31
    const int qt = q >> 5, ql = q & 31, ct = c2 >> 5, c5 = c2 & 31;
    const int hb = (c5 >> 2) & 1;
    const int jw = ((c5 & 2) >> 1) | ((c5 >> 3) << 1);
    const size_t widx = (((size_t)qt * 2 + ct) * 512) + (hb * 32 + ql) * 8 + jw;
    float lo = 0.f, hi = 0.f, ps = 0.f;
#pragma unroll
    for (int s = 0; s < 4; ++s) {
        int yb = s * 8 + ib;
        uint32_t u = pacc32[(size_t)yb * (128 * 2 * 512) + widx];
        lo += bf2f((u16)(u & 0xffff));
        hi += bf2f((u16)(u >> 16));
        ps += ppsum[(size_t)yb * 4096 + q];
    }
    float rs = gamma[i] / ps;
    size_t base = ((size_t)ib * 4096 + q) * 64 + c2;
    uint32_t bv = *(const uint32_t*)(b_bf + base);
    float o0 = rs * lo + bf2f((u16)(bv & 0xffff));
    float o1 = rs * hi + bf2f((u16)(bv >> 16));
    uint32_t ou = ((uint32_t)f2bf(o1) << 16) | f2bf(o0);
    *(uint32_t*)(fusedbf + ((size_t)b * 4096 + q) * 256 + i * 64 + c2) = ou;
}

// ---------------- K5: fused TF-SAME avg pool + 1x1 conv 256->16 + BN ------
// compact 1D grid 718: j0:[0,512) j1:[512,640) j2:[640,702) j3:[702,718)
__global__ __launch_bounds__(256) void pconv_k(
    const u16* __restrict__ fusedbf,
    const float* __restrict__ pw, const float* __restrict__ pbias,
    const float* __restrict__ pg, const float* __restrict__ pbe,
    const float* __restrict__ pm, const float* __restrict__ pv,
    float* __restrict__ po0, float* __restrict__ po1,
    float* __restrict__ po2, float* __restrict__ po3)
{
    __shared__ float plds[16][257];
    int id = blockIdx.x;
    int j, b, bx;
    if (id < 512)      { j = 0; b = id >> 8; bx = id & 255; }
    else if (id < 640) { int t = id - 512; j = 1; b = t >> 6; bx = t & 63; }
    else if (id < 702) { int t = id - 640; j = 2; b = (t >= 31); bx = (t >= 31) ? t - 31 : t; }
    else               { int t = id - 702; j = 3; b = t >> 3; bx = t & 7; }
    const int npix = (j == 0) ? 4096 : (j == 1) ? 1024 : (j == 2) ? 484 : 121;
    const int co = threadIdx.x & 15;
    const int pixl = threadIdx.x >> 4;
    const int pix = bx * 16 + pixl;
    const float* wp = pw + (size_t)j * 256 * 16 + co;
    float acc = pbias[j * 16 + co];

    if (j == 0) {
        const u16* ip = fusedbf + ((size_t)b * 4096 + pix) * 256;
        for (int c8 = 0; c8 < 32; ++c8) {
            bs8 xv = *(const bs8*)(ip + c8 * 8);
#pragma unroll
            for (int e = 0; e < 8; ++e)
                acc = fmaf(bf2f((u16)xv[e]), wp[(c8 * 8 + e) * 16], acc);
        }
    } else {
        const int ps = (j == 1) ? 2 : (j == 2) ? 3 : 6;
        const int od = (j == 1) ? 32 : (j == 2) ? 22 : 11;
        if (pix < npix) {
            const int oh = pix / od, ow = pix % od;
            const int pad = (od * ps - 64) >> 1;
            int hs = oh * ps - pad, wss = ow * ps - pad;
            int h0 = max(hs, 0), h1 = min(hs + ps, 64);
            int w0 = max(wss, 0), w1 = min(wss + ps, 64);
            float s[16];
#pragma unroll
            for (int e = 0; e < 16; ++e) s[e] = 0.f;
            for (int hh = h0; hh < h1; ++hh)
                for (int ww = w0; ww < w1; ++ww) {
                    const u16* p = fusedbf + (((size_t)b * 4096) + hh * 64 + ww) * 256 + co * 16;
                    bs8 v0 = *(const bs8*)(p);
                    bs8 v1 = *(const bs8*)(p + 8);
#pragma unroll
                    for (int e = 0; e < 8; ++e) {
                        s[e] += bf2f((u16)v0[e]);
                        s[8 + e] += bf2f((u16)v1[e]);
                    }
                }
            float inv = 1.f / (float)((h1 - h0) * (w1 - w0));
#pragma unroll
            for (int e = 0; e < 16; ++e) plds[pixl][co * 16 + e] = s[e] * inv;
        }
        __syncthreads();
        if (pix < npix)
            for (int c = 0; c < 256; ++c)
                acc = fmaf(plds[pixl][c], wp[c * 16], acc);
    }
    if (pix < npix) {
        acc = (acc - pm[j * 16 + co]) * (pg[j * 16 + co] * rsqrtf(pv[j * 16 + co] + EPSBN)) + pbe[j * 16 + co];
        float* outp = (j == 0) ? po0 : (j == 1) ? po1 : (j == 2) ? po2 : po3;
        outp[((size_t)b * npix + pix) * 16 + co] = acc;
    }
}

// ---------------- K6: final 320->64 GEMM (inline bilinear) + BN + ReLU -----
__global__ __launch_bounds__(64) void final_gemm_k(
    const u16* __restrict__ fusedbf, const float* __restrict__ po0,
    const float* __restrict__ po1, const float* __restrict__ po2,
    const float* __restrict__ po3, const u16* __restrict__ wfin_pk,
    const float* __restrict__ pjb, const float* __restrict__ g,
    const float* __restrict__ be, const float* __restrict__ m,
    const float* __restrict__ v, float* __restrict__ out)
{
    const int gpix0 = blockIdx.x * 16;
    const int lane = threadIdx.x & 63;
    const int gg = lane >> 4, r = lane & 15;

    const int p = gpix0 + r;
    const int b = p >> 12, hw = p & 4095, h = hw >> 6, w = hw & 63;
    bs8 pav[2];
#pragma unroll
    for (int t = 0; t < 2; ++t) {
        int jj = t * 2 + (gg >> 1);
        int cc0 = (gg & 1) * 8;
        const float* P = (jj == 0) ? po0 : (jj == 1) ? po1 : (jj == 2) ? po2 : po3;
        int od = (jj == 0) ? 64 : (jj == 1) ? 32 : (jj == 2) ? 22 : 11;
        float scale = (float)od / 64.f;
        float fy = (h + 0.5f) * scale - 0.5f;
        int y0 = (int)floorf(fy);
        float ay = fy - (float)y0;
        int y1 = min(y0 + 1, od - 1);
        y0 = max(y0, 0);
        float fx = (w + 0.5f) * scale - 0.5f;
        int x0 = (int)floorf(fx);
        float ax = fx - (float)x0;
        int x1 = min(x0 + 1, od - 1);
        x0 = max(x0, 0);
        const float* B0 = P + (size_t)b * od * od * 16 + cc0;
        const float* p00 = B0 + (size_t)(y0 * od + x0) * 16;
        const float* p01 = B0 + (size_t)(y0 * od + x1) * 16;
        const float* p10 = B0 + (size_t)(y1 * od + x0) * 16;
        const float* p11 = B0 + (size_t)(y1 * od + x1) * 16;
        union { u16 s[8]; bs8 v8; } o;
#pragma unroll
        for (int cc = 0; cc < 8; ++cc) {
            float top = p00[cc] + ax * (p01[cc] - p00[cc]);
            float bot = p10[cc] + ax * (p11[cc] - p10[cc]);
            o.s[cc] = f2bf(top + ay * (bot - top));
        }
        pav[t] = o.v8;
    }

    vf4 acc[4];
#pragma unroll
    for (int ct = 0; ct < 4; ++ct) acc[ct] = (vf4){0.f, 0.f, 0.f, 0.f};

    const u16* fa = fusedbf + (size_t)p * 256 + gg * 8;
#pragma unroll
    for (int kc = 0; kc < 10; ++kc) {
        bs8 av = (kc < 8) ? *(const bs8*)(fa + kc * 32) : pav[kc - 8];
        const u16* wb = wfin_pk + (size_t)((kc * 4 + gg) * 4) * 128 + r * 8;
#pragma unroll
        for (int ct = 0; ct < 4; ++ct) {
            bs8 bv = *(const bs8*)(wb + ct * 128);
            acc[ct] = __builtin_amdgcn_mfma_f32_16x16x32_bf16(av, bv, acc[ct], 0, 0, 0);
        }
    }
#pragma unroll
    for (int ct = 0; ct < 4; ++ct) {
        int c = ct * 16 + r;
        float sc = g[c] * rsqrtf(v[c] + EPSBN);
        float sh = (pjb[c] - m[c]) * sc + be[c];
#pragma unroll
        for (int reg = 0; reg < 4; ++reg) {
            int pix = gpix0 + gg * 4 + reg;
            out[(size_t)pix * 64 + c] = fmaxf(acc[ct][reg] * sc + sh, 0.f);
        }
    }
}

extern "C" void kernel_launch(void* const* d_in, const int* in_sizes, int n_in,
                              void* d_out, int out_size, void* d_ws, size_t ws_size,
                              hipStream_t stream)
{
    const float* x      = (const float*)d_in[0];
    const float* conv_w = (const float*)d_in[1];
    const float* conv_b = (const float*)d_in[2];
    const float* bn_g   = (const float*)d_in[3];
    const float* bn_b   = (const float*)d_in[4];
    const float* bn_m   = (const float*)d_in[5];
    const float* bn_v   = (const float*)d_in[6];
    const float* q_w    = (const float*)d_in[7];
    const float* q_b    = (const float*)d_in[8];
    const float* k_w    = (const float*)d_in[9];
    const float* k_b    = (const float*)d_in[10];
    const float* v_w    = (const float*)d_in[11];
    const float* v_b    = (const float*)d_in[12];
    const float* gamma  = (const float*)d_in[13];
    const float* ppl_w  = (const float*)d_in[14];
    const float* ppl_b  = (const float*)d_in[15];
    const float* ppl_g  = (const float*)d_in[16];
    const float* ppl_be = (const float*)d_in[17];
    const float* ppl_m  = (const float*)d_in[18];
    const float* ppl_v  = (const float*)d_in[19];
    const float* proj_w = (const float*)d_in[20];
    const float* proj_b = (const float*)d_in[21];
    const float* pbn_g  = (const float*)d_in[22];
    const float* pbn_b  = (const float*)d_in[23];
    const float* pbn_m  = (const float*)d_in[24];
    const float* pbn_v  = (const float*)d_in[25];

    char* ws = (char*)d_ws;
    u16*  xbf     = (u16*)(ws + 0);             // 1,048,576
    u16*  wpk     = (u16*)(ws + 1048576);       //   294,912
    u16*  wqk_pk  = (u16*)(ws + 1343488);       //     8,192
    u16*  wv_pk   = (u16*)(ws + 1351680);       //    32,768
    u16*  wfin_pk = (u16*)(ws + 1384448);       //    40,960
    u16*  b_bf    = (u16*)(ws + 1425408);       // 4,194,304  [8][4096][64]
    u16*  qbuf    = (u16*)(ws + 5619712);       //   524,288
    u16*  kbuf    = (u16*)(ws + 6144000);       //   524,288
    u16*  vT      = (u16*)(ws + 6668288);       // 4,194,304  [8][64][4096]
    u16*  fusedbf = (u16*)(ws + 10862592);      // 4,194,304  [2][4096][256]
    float* ppsum  = (float*)(ws + 15056896);    //   524,288  [32][4096]
    uint32_t* pacc32 = (uint32_t*)(ws + 15581184); // 16,777,216 [32][128][2][512] u32
    // po buffers reuse the pacc region (dead after combine_k):
    float* po0    = (float*)(ws + 18917376);    //   524,288
    float* po1    = (float*)(ws + 19441664);    //   131,072
    float* po2    = (float*)(ws + 19572736);    //    61,952
    float* po3    = (float*)(ws + 19634688);    //    15,488
    float* out    = (float*)d_out;

    prep_k<<<dim3(560), 256, 0, stream>>>(
        x, conv_w, q_w, k_w, v_w, proj_w, xbf, wpk, wqk_pk, wv_pk, wfin_pk);
    conv_mfma_k<<<dim3(1024), 256, 0, stream>>>(
        xbf, wpk, conv_b, bn_g, bn_b, bn_m, bn_v,
        wqk_pk, wv_pk, q_b, k_b, v_b, b_bf, qbuf, kbuf, vT);
    attn_k<<<dim3(512), 256, 0, stream>>>(qbuf, kbuf, vT, pacc32, ppsum);
    combine_k<<<dim3(4096), 256, 0, stream>>>(pacc32, ppsum, b_bf, gamma, fusedbf);
    pconv_k<<<dim3(718), 256, 0, stream>>>(
        fusedbf, ppl_w, ppl_b, ppl_g, ppl_be, ppl_m, ppl_v,
        po0, po1, po2, po3);
    final_gemm_k<<<dim3(512), 64, 0, stream>>>(
        fusedbf, po0, po1, po2, po3, wfin_pk, proj_b, pbn_g, pbn_b, pbn_m, pbn_v, out);
}